// Round 1
// baseline (12251.531 us; speedup 1.0000x reference)
//
#include <hip/hip_runtime.h>
#include <hip/hip_bf16.h>
#include <math.h>

#define N_DRUG 20000
#define N_GENE 40000
#define HID 128
#define NEDGE 800000
#define NBATCH 4096

// ---------- helpers ----------
__device__ inline unsigned f2ord(float f) {
    unsigned u = __float_as_uint(f);
    return (u & 0x80000000u) ? ~u : (u | 0x80000000u);
}
__device__ inline float ord2f(unsigned u) {
    unsigned v = (u & 0x80000000u) ? (u ^ 0x80000000u) : ~u;
    return __uint_as_float(v);
}
__device__ inline float gelu_exact(float x) {
    return 0.5f * x * (1.f + erff(x * 0.70710678118654752f));
}

// ---------- 1. fuse relation matrices + p_rel scale into k/v projection weights ----------
// Output BF[lt][k][j], j<128: qW; 128..256: kW @ a_rel * p/sqrt(D); 256..384: vW @ m_rel
// BB[lt][j]: matching biases.
__global__ void fuse_weights(const float* __restrict__ kW, const float* __restrict__ kb,
                             const float* __restrict__ qW, const float* __restrict__ qb,
                             const float* __restrict__ vW, const float* __restrict__ vb,
                             const float* __restrict__ a_rel, const float* __restrict__ m_rel,
                             const float* __restrict__ p_rel,
                             float* __restrict__ BF, float* __restrict__ BB) {
    int idx = blockIdx.x * 256 + threadIdx.x;          // over 2*2*128*384
    if (idx >= 2 * 2 * 128 * 384) return;
    int j = idx % 384;
    int k = (idx / 384) % 128;
    int lt = idx / (384 * 128);                        // l*2 + t
    const float rs = 0.17677669529663687f;             // 1/sqrt(32)
    float w, b;
    if (j < 128) {
        w = qW[(lt * 128 + k) * 128 + j];
        b = qb[lt * 128 + j];
    } else if (j < 256) {
        int c = j - 128, h = c >> 5, e = c & 31;
        float scale = p_rel[lt * 4 + h] * rs;
        const float* ar = a_rel + ((lt * 4 + h) * 32) * 32;   // [d][e]
        const float* kWr = kW + (lt * 128 + k) * 128 + h * 32;
        const float* kbr = kb + lt * 128 + h * 32;
        float s = 0.f, sb = 0.f;
        for (int d = 0; d < 32; d++) { float a = ar[d * 32 + e]; s += kWr[d] * a; sb += kbr[d] * a; }
        w = s * scale; b = sb * scale;
    } else {
        int c = j - 256, h = c >> 5, e = c & 31;
        const float* mr = m_rel + ((lt * 4 + h) * 32) * 32;
        const float* vWr = vW + (lt * 128 + k) * 128 + h * 32;
        const float* vbr = vb + lt * 128 + h * 32;
        float s = 0.f, sb = 0.f;
        for (int d = 0; d < 32; d++) { float m = mr[d * 32 + e]; s += vWr[d] * m; sb += vbr[d] * m; }
        w = s; b = sb;
    }
    BF[(lt * 128 + k) * 384 + j] = w;
    if (k == 0) BB[lt * 384 + j] = b;
}

// ---------- 2. f32 GEMM: C[N,M] = A[N,128] @ B[128,M] + bias ----------
// mode 0: plain. mode 1: g=sigmoid(*skipPtr); C = relu(g*(acc+bias) + (1-g)*Xcur), ldc=128.
__global__ __launch_bounds__(256) void gemm128(const float* __restrict__ A, int N,
                                               const float* __restrict__ B, int ldb,
                                               const float* __restrict__ bias,
                                               float* __restrict__ C, int ldc,
                                               int mode, const float* __restrict__ skipPtr,
                                               const float* __restrict__ Xcur) {
    __shared__ float As[128][64];   // [k][row ^ swz(k)]
    __shared__ float Bs[128][64];   // [k][jj]
    const int tid = threadIdx.x;
    const int rowBase = blockIdx.y * 64;
    const int colBase = blockIdx.x * 64;

#pragma unroll
    for (int it = 0; it < 8; ++it) {
        int lin = it * 256 + tid;            // 0..2047 float4 units
        // A: 64 rows x 32 float4 along k
        int row = lin >> 5;
        int kq  = lin & 31;
        float4 av = make_float4(0.f, 0.f, 0.f, 0.f);
        int gr = rowBase + row;
        if (gr < N) av = *(const float4*)(A + (size_t)gr * 128 + kq * 4);
        int rs = row ^ ((kq & 7) << 2);      // XOR swizzle to spread banks
        As[kq * 4 + 0][rs] = av.x;
        As[kq * 4 + 1][rs] = av.y;
        As[kq * 4 + 2][rs] = av.z;
        As[kq * 4 + 3][rs] = av.w;
        // B: 128 k x 16 float4 along j
        int bk = lin >> 4;
        int jq = lin & 15;
        float4 bv = *(const float4*)(B + (size_t)bk * ldb + colBase + jq * 4);
        *(float4*)&Bs[bk][jq * 4] = bv;
    }
    __syncthreads();

    const int tr = tid >> 4, tc = tid & 15;
    float acc[4][4] = {};
#pragma unroll 8
    for (int k = 0; k < 128; k++) {
        int swz = (((k >> 2) & 7) << 2);
        float4 a4 = *(const float4*)&As[k][(tr * 4) ^ swz];
        float4 b4 = *(const float4*)&Bs[k][tc * 4];
        float ar[4] = {a4.x, a4.y, a4.z, a4.w};
        float br[4] = {b4.x, b4.y, b4.z, b4.w};
#pragma unroll
        for (int i = 0; i < 4; i++)
#pragma unroll
            for (int j = 0; j < 4; j++) acc[i][j] += ar[i] * br[j];
    }

    float g = 0.f;
    if (mode == 1) g = 1.f / (1.f + expf(-skipPtr[0]));
    const int gc = colBase + tc * 4;
    float4 bb = *(const float4*)(bias + gc);
    float bias4[4] = {bb.x, bb.y, bb.z, bb.w};
#pragma unroll
    for (int i = 0; i < 4; i++) {
        int gr = rowBase + tr * 4 + i;
        if (gr >= N) continue;
        float o[4];
#pragma unroll
        for (int j = 0; j < 4; j++) o[j] = acc[i][j] + bias4[j];
        if (mode == 1) {
            float4 xv = *(const float4*)(Xcur + (size_t)gr * 128 + gc);
            float xr[4] = {xv.x, xv.y, xv.z, xv.w};
#pragma unroll
            for (int j = 0; j < 4; j++) o[j] = fmaxf(g * o[j] + (1.f - g) * xr[j], 0.f);
        }
        *(float4*)(C + (size_t)gr * ldc + gc) = make_float4(o[0], o[1], o[2], o[3]);
    }
}

// ---------- 3. edge pass A: alpha + segment max ----------
// 16 lanes per edge: lane j -> head h=j>>2, part p=j&3 (8 dims each)
__global__ __launch_bounds__(256) void edge_pass_a(const int* __restrict__ src,
                                                   const int* __restrict__ dst,
                                                   const float* __restrict__ qkvS,
                                                   const float* __restrict__ qkvD,
                                                   float* __restrict__ alpha,
                                                   unsigned* __restrict__ amax) {
    int gt = blockIdx.x * 256 + threadIdx.x;
    int e = gt >> 4;
    int j = gt & 15;
    if (e >= NEDGE) return;
    int h = j >> 2, p = j & 3;
    int s = src[e], d = dst[e];
    const float* qp = qkvD + (size_t)d * 384 + h * 32 + p * 8;          // q at offset 0
    const float* kp = qkvS + (size_t)s * 384 + 128 + h * 32 + p * 8;    // kr at offset 128
    float4 q0 = *(const float4*)qp, q1 = *(const float4*)(qp + 4);
    float4 k0 = *(const float4*)kp, k1 = *(const float4*)(kp + 4);
    float sd = q0.x * k0.x + q0.y * k0.y + q0.z * k0.z + q0.w * k0.w
             + q1.x * k1.x + q1.y * k1.y + q1.z * k1.z + q1.w * k1.w;
    sd += __shfl_xor(sd, 1);
    sd += __shfl_xor(sd, 2);
    if (p == 0) {
        alpha[(size_t)e * 4 + h] = sd;
        atomicMax(amax + (size_t)d * 4 + h, f2ord(sd));
    }
}

// ---------- 4. edge pass B: a = exp(alpha - max); num += a*vr; den += a ----------
__global__ __launch_bounds__(256) void edge_pass_b(const int* __restrict__ src,
                                                   const int* __restrict__ dst,
                                                   const float* __restrict__ qkvS,
                                                   const float* __restrict__ alpha,
                                                   const unsigned* __restrict__ amax,
                                                   float* __restrict__ denom,
                                                   float* __restrict__ num) {
    int gt = blockIdx.x * 256 + threadIdx.x;
    int e = gt >> 4;
    int j = gt & 15;
    if (e >= NEDGE) return;
    int h = j >> 2, p = j & 3;
    int s = src[e], d = dst[e];
    float al = alpha[(size_t)e * 4 + h];
    float m = ord2f(amax[(size_t)d * 4 + h]);
    float a = expf(al - m);
    if (p == 0) atomicAdd(denom + (size_t)d * 4 + h, a);
    const float* vp = qkvS + (size_t)s * 384 + 256 + h * 32 + p * 8;    // vr at offset 256
    float4 v0 = *(const float4*)vp, v1 = *(const float4*)(vp + 4);
    float* np = num + (size_t)d * 128 + h * 32 + p * 8;
    atomicAdd(np + 0, a * v0.x);
    atomicAdd(np + 1, a * v0.y);
    atomicAdd(np + 2, a * v0.z);
    atomicAdd(np + 3, a * v0.w);
    atomicAdd(np + 4, a * v1.x);
    atomicAdd(np + 5, a * v1.y);
    atomicAdd(np + 6, a * v1.z);
    atomicAdd(np + 7, a * v1.w);
}

// ---------- 5. normalize by denom + exact GELU (in place) ----------
__global__ void norm_gelu(float* __restrict__ num, const float* __restrict__ denom, int N) {
    int idx = blockIdx.x * 256 + threadIdx.x;   // over N*32 float4s
    if (idx >= N * 32) return;
    int n = idx >> 5, q = idx & 31;
    float den = denom[n * 4 + (q >> 3)] + 1e-16f;
    float4 v = *(float4*)(num + (size_t)n * 128 + q * 4);
    v.x = gelu_exact(v.x / den);
    v.y = gelu_exact(v.y / den);
    v.z = gelu_exact(v.z / den);
    v.w = gelu_exact(v.w / den);
    *(float4*)(num + (size_t)n * 128 + q * 4) = v;
}

// ---------- 6. column sum over genes ----------
__global__ __launch_bounds__(128) void colsum(const float* __restrict__ X, int N,
                                              float* __restrict__ out) {
    int c = threadIdx.x;   // 128
    float s = 0.f;
    for (int r = blockIdx.x; r < N; r += gridDim.x) s += X[(size_t)r * 128 + c];
    atomicAdd(out + c, s);
}

// ---------- 7. predictor MLP ----------
__global__ __launch_bounds__(128) void predictor(const float* __restrict__ Xd,
                                                 const float* __restrict__ gsum,
                                                 const int* __restrict__ didx,
                                                 const float* __restrict__ pW1,
                                                 const float* __restrict__ pb1,
                                                 const float* __restrict__ pW2,
                                                 const float* __restrict__ pb2,
                                                 float* __restrict__ out) {
    __shared__ float comb[256];
    __shared__ float red[128];
    int b = blockIdx.x, t = threadIdx.x;
    int dn = didx[b];
    comb[t]       = Xd[(size_t)dn * 128 + t];
    comb[128 + t] = gsum[t] * (1.f / 40000.f);
    __syncthreads();
    float acc = pb1[t];
    for (int i = 0; i < 256; i++) acc += comb[i] * pW1[i * 128 + t];
    acc = fmaxf(acc, 0.f);
    red[t] = acc * pW2[t];
    __syncthreads();
    for (int sft = 64; sft > 0; sft >>= 1) {
        if (t < sft) red[t] += red[t + sft];
        __syncthreads();
    }
    if (t == 0) out[b] = red[0] + pb2[0];
}

// ---------- launch ----------
extern "C" void kernel_launch(void* const* d_in, const int* in_sizes, int n_in,
                              void* d_out, int out_size, void* d_ws, size_t ws_size,
                              hipStream_t stream) {
    const float* x_drug = (const float*)d_in[0];
    const float* x_gene = (const float*)d_in[1];
    const float* kW = (const float*)d_in[2];
    const float* kb = (const float*)d_in[3];
    const float* qW = (const float*)d_in[4];
    const float* qb = (const float*)d_in[5];
    const float* vW = (const float*)d_in[6];
    const float* vb = (const float*)d_in[7];
    const float* aW = (const float*)d_in[8];
    const float* ab = (const float*)d_in[9];
    const float* skip = (const float*)d_in[10];
    const float* a_rel = (const float*)d_in[11];
    const float* m_rel = (const float*)d_in[12];
    const float* p_rel = (const float*)d_in[13];
    const float* pW1 = (const float*)d_in[14];
    const float* pb1 = (const float*)d_in[15];
    const float* pW2 = (const float*)d_in[16];
    const float* pb2 = (const float*)d_in[17];
    const int* e_dg_s = (const int*)d_in[18];
    const int* e_dg_d = (const int*)d_in[19];
    const int* e_gd_s = (const int*)d_in[20];
    const int* e_gd_d = (const int*)d_in[21];
    const int* drug_idx = (const int*)d_in[22];

    float* ws = (float*)d_ws;
    // workspace layout (floats)
    float* BF    = ws;                         // 2*2*128*384 = 196608
    float* BB    = BF + 196608;                // 2*2*384 = 3072
    float* QKVD  = BB + 3072;                  // 20000*384
    float* QKVG  = QKVD + (size_t)N_DRUG * 384;// 40000*384
    float* XD0   = QKVG + (size_t)N_GENE * 384;
    float* XD1   = XD0 + (size_t)N_DRUG * 128;
    float* XG0   = XD1 + (size_t)N_DRUG * 128;
    float* XG1   = XG0 + (size_t)N_GENE * 128;
    float* A_DG  = XG1 + (size_t)N_GENE * 128; // 800000*4
    float* A_GD  = A_DG + (size_t)NEDGE * 4;
    unsigned* AMAXG = (unsigned*)(A_GD + (size_t)NEDGE * 4);  // 40000*4
    unsigned* AMAXD = AMAXG + (size_t)N_GENE * 4;             // 20000*4
    float* DENG  = (float*)(AMAXD + (size_t)N_DRUG * 4);
    float* DEND  = DENG + (size_t)N_GENE * 4;
    float* NUMG  = DEND + (size_t)N_DRUG * 4;  // 40000*128
    float* NUMD  = NUMG + (size_t)N_GENE * 128;// 20000*128
    float* GSUM  = NUMD + (size_t)N_DRUG * 128;// 128

    fuse_weights<<<768, 256, 0, stream>>>(kW, kb, qW, qb, vW, vb, a_rel, m_rel, p_rel, BF, BB);

    const float* xd_cur = x_drug;
    const float* xg_cur = x_gene;
    float* xd_bufs[2] = {XD0, XD1};
    float* xg_bufs[2] = {XG0, XG1};

    const int gridD = (N_DRUG + 63) / 64;   // 313
    const int gridG = (N_GENE + 63) / 64;   // 625

    for (int l = 0; l < 2; ++l) {
        const float* BFd = BF + (size_t)(l * 2 + 0) * 49152;
        const float* BFg = BF + (size_t)(l * 2 + 1) * 49152;
        const float* BBd = BB + (size_t)(l * 2 + 0) * 384;
        const float* BBg = BB + (size_t)(l * 2 + 1) * 384;

        gemm128<<<dim3(6, gridD), 256, 0, stream>>>(xd_cur, N_DRUG, BFd, 384, BBd, QKVD, 384, 0, nullptr, nullptr);
        gemm128<<<dim3(6, gridG), 256, 0, stream>>>(xg_cur, N_GENE, BFg, 384, BBg, QKVG, 384, 0, nullptr, nullptr);

        hipMemsetAsync(AMAXG, 0, (size_t)N_GENE * 4 * sizeof(unsigned), stream);
        hipMemsetAsync(AMAXD, 0, (size_t)N_DRUG * 4 * sizeof(unsigned), stream);
        hipMemsetAsync(DENG, 0, (size_t)N_GENE * 4 * sizeof(float), stream);
        hipMemsetAsync(DEND, 0, (size_t)N_DRUG * 4 * sizeof(float), stream);
        hipMemsetAsync(NUMG, 0, (size_t)N_GENE * 128 * sizeof(float), stream);
        hipMemsetAsync(NUMD, 0, (size_t)N_DRUG * 128 * sizeof(float), stream);

        // edge type 0: drug -> gene (src drugs, dst genes)
        edge_pass_a<<<50000, 256, 0, stream>>>(e_dg_s, e_dg_d, QKVD, QKVG, A_DG, AMAXG);
        // edge type 1: gene -> drug
        edge_pass_a<<<50000, 256, 0, stream>>>(e_gd_s, e_gd_d, QKVG, QKVD, A_GD, AMAXD);

        edge_pass_b<<<50000, 256, 0, stream>>>(e_dg_s, e_dg_d, QKVD, A_DG, AMAXG, DENG, NUMG);
        edge_pass_b<<<50000, 256, 0, stream>>>(e_gd_s, e_gd_d, QKVG, A_GD, AMAXD, DEND, NUMD);

        norm_gelu<<<(N_GENE * 32 + 255) / 256, 256, 0, stream>>>(NUMG, DENG, N_GENE);
        norm_gelu<<<(N_DRUG * 32 + 255) / 256, 256, 0, stream>>>(NUMD, DEND, N_DRUG);

        float* xd_next = xd_bufs[l];
        float* xg_next = xg_bufs[l];
        gemm128<<<dim3(2, gridD), 256, 0, stream>>>(NUMD, N_DRUG, aW + (size_t)(l * 2 + 0) * 16384, 128,
                                                    ab + (size_t)(l * 2 + 0) * 128, xd_next, 128,
                                                    1, skip + (l * 2 + 0), xd_cur);
        gemm128<<<dim3(2, gridG), 256, 0, stream>>>(NUMG, N_GENE, aW + (size_t)(l * 2 + 1) * 16384, 128,
                                                    ab + (size_t)(l * 2 + 1) * 128, xg_next, 128,
                                                    1, skip + (l * 2 + 1), xg_cur);
        xd_cur = xd_next;
        xg_cur = xg_next;
    }

    hipMemsetAsync(GSUM, 0, 128 * sizeof(float), stream);
    colsum<<<256, 128, 0, stream>>>(xg_cur, N_GENE, GSUM);
    predictor<<<NBATCH, 128, 0, stream>>>(xd_cur, GSUM, drug_idx, pW1, pb1, pW2, pb2, (float*)d_out);
}

// Round 2
// 1216.405 us; speedup vs baseline: 10.0719x; 10.0719x over previous
//
#include <hip/hip_runtime.h>
#include <hip/hip_bf16.h>
#include <math.h>

#define N_DRUG 20000
#define N_GENE 40000
#define HID 128
#define NEDGE 800000
#define NBATCH 4096

// ---------- helpers ----------
__device__ inline float gelu_exact(float x) {
    return 0.5f * x * (1.f + erff(x * 0.70710678118654752f));
}

// ---------- 1. fuse relation matrices + p_rel scale into k/v projection weights ----------
// Output BF[lt][k][j], j<128: qW; 128..256: kW @ a_rel * p/sqrt(D); 256..384: vW @ m_rel
// BB[lt][j]: matching biases.
__global__ void fuse_weights(const float* __restrict__ kW, const float* __restrict__ kb,
                             const float* __restrict__ qW, const float* __restrict__ qb,
                             const float* __restrict__ vW, const float* __restrict__ vb,
                             const float* __restrict__ a_rel, const float* __restrict__ m_rel,
                             const float* __restrict__ p_rel,
                             float* __restrict__ BF, float* __restrict__ BB) {
    int idx = blockIdx.x * 256 + threadIdx.x;          // over 2*2*128*384
    if (idx >= 2 * 2 * 128 * 384) return;
    int j = idx % 384;
    int k = (idx / 384) % 128;
    int lt = idx / (384 * 128);                        // l*2 + t
    const float rs = 0.17677669529663687f;             // 1/sqrt(32)
    float w, b;
    if (j < 128) {
        w = qW[(lt * 128 + k) * 128 + j];
        b = qb[lt * 128 + j];
    } else if (j < 256) {
        int c = j - 128, h = c >> 5, e = c & 31;
        float scale = p_rel[lt * 4 + h] * rs;
        const float* ar = a_rel + ((lt * 4 + h) * 32) * 32;   // [d][e]
        const float* kWr = kW + (lt * 128 + k) * 128 + h * 32;
        const float* kbr = kb + lt * 128 + h * 32;
        float s = 0.f, sb = 0.f;
        for (int d = 0; d < 32; d++) { float a = ar[d * 32 + e]; s += kWr[d] * a; sb += kbr[d] * a; }
        w = s * scale; b = sb * scale;
    } else {
        int c = j - 256, h = c >> 5, e = c & 31;
        const float* mr = m_rel + ((lt * 4 + h) * 32) * 32;
        const float* vWr = vW + (lt * 128 + k) * 128 + h * 32;
        const float* vbr = vb + lt * 128 + h * 32;
        float s = 0.f, sb = 0.f;
        for (int d = 0; d < 32; d++) { float m = mr[d * 32 + e]; s += vWr[d] * m; sb += vbr[d] * m; }
        w = s; b = sb;
    }
    BF[(lt * 128 + k) * 384 + j] = w;
    if (k == 0) BB[lt * 384 + j] = b;
}

// ---------- 2. f32 GEMM: C[N,M] = A[N,128] @ B[128,M] + bias ----------
// mode 0: plain. mode 1: g=sigmoid(*skipPtr); C = relu(g*(acc+bias) + (1-g)*Xcur), ldc=128.
__global__ __launch_bounds__(256) void gemm128(const float* __restrict__ A, int N,
                                               const float* __restrict__ B, int ldb,
                                               const float* __restrict__ bias,
                                               float* __restrict__ C, int ldc,
                                               int mode, const float* __restrict__ skipPtr,
                                               const float* __restrict__ Xcur) {
    __shared__ float As[128][64];   // [k][row ^ swz(k)]
    __shared__ float Bs[128][64];   // [k][jj]
    const int tid = threadIdx.x;
    const int rowBase = blockIdx.y * 64;
    const int colBase = blockIdx.x * 64;

#pragma unroll
    for (int it = 0; it < 8; ++it) {
        int lin = it * 256 + tid;            // 0..2047 float4 units
        // A: 64 rows x 32 float4 along k
        int row = lin >> 5;
        int kq  = lin & 31;
        float4 av = make_float4(0.f, 0.f, 0.f, 0.f);
        int gr = rowBase + row;
        if (gr < N) av = *(const float4*)(A + (size_t)gr * 128 + kq * 4);
        int rs = row ^ ((kq & 7) << 2);      // XOR swizzle to spread banks
        As[kq * 4 + 0][rs] = av.x;
        As[kq * 4 + 1][rs] = av.y;
        As[kq * 4 + 2][rs] = av.z;
        As[kq * 4 + 3][rs] = av.w;
        // B: 128 k x 16 float4 along j
        int bk = lin >> 4;
        int jq = lin & 15;
        float4 bv = *(const float4*)(B + (size_t)bk * ldb + colBase + jq * 4);
        *(float4*)&Bs[bk][jq * 4] = bv;
    }
    __syncthreads();

    const int tr = tid >> 4, tc = tid & 15;
    float acc[4][4] = {};
#pragma unroll 8
    for (int k = 0; k < 128; k++) {
        int swz = (((k >> 2) & 7) << 2);
        float4 a4 = *(const float4*)&As[k][(tr * 4) ^ swz];
        float4 b4 = *(const float4*)&Bs[k][tc * 4];
        float ar[4] = {a4.x, a4.y, a4.z, a4.w};
        float br[4] = {b4.x, b4.y, b4.z, b4.w};
#pragma unroll
        for (int i = 0; i < 4; i++)
#pragma unroll
            for (int j = 0; j < 4; j++) acc[i][j] += ar[i] * br[j];
    }

    float g = 0.f;
    if (mode == 1) g = 1.f / (1.f + expf(-skipPtr[0]));
    const int gc = colBase + tc * 4;
    float4 bb = *(const float4*)(bias + gc);
    float bias4[4] = {bb.x, bb.y, bb.z, bb.w};
#pragma unroll
    for (int i = 0; i < 4; i++) {
        int gr = rowBase + tr * 4 + i;
        if (gr >= N) continue;
        float o[4];
#pragma unroll
        for (int j = 0; j < 4; j++) o[j] = acc[i][j] + bias4[j];
        if (mode == 1) {
            float4 xv = *(const float4*)(Xcur + (size_t)gr * 128 + gc);
            float xr[4] = {xv.x, xv.y, xv.z, xv.w};
#pragma unroll
            for (int j = 0; j < 4; j++) o[j] = fmaxf(g * o[j] + (1.f - g) * xr[j], 0.f);
        }
        *(float4*)(C + (size_t)gr * ldc + gc) = make_float4(o[0], o[1], o[2], o[3]);
    }
}

// ---------- 3. CSR build: histogram ----------
__global__ void hist_kernel(const int* __restrict__ dst, int* __restrict__ cnt) {
    int e = blockIdx.x * 256 + threadIdx.x;
    if (e < NEDGE) atomicAdd(cnt + dst[e], 1);
}

// ---------- 4. CSR build: single-block exclusive scan (n up to ~64K) ----------
__global__ __launch_bounds__(1024) void exscan(const int* __restrict__ cnt, int n,
                                               int* __restrict__ rowStart) {
    __shared__ int tmp[1024];
    __shared__ int carry;
    int t = threadIdx.x;
    if (t == 0) carry = 0;
    __syncthreads();
    for (int base = 0; base < n; base += 1024) {
        int v = (base + t < n) ? cnt[base + t] : 0;
        tmp[t] = v;
        __syncthreads();
        for (int off = 1; off < 1024; off <<= 1) {
            int add = (t >= off) ? tmp[t - off] : 0;
            __syncthreads();
            tmp[t] += add;
            __syncthreads();
        }
        if (base + t < n) rowStart[base + t] = carry + tmp[t] - v;
        __syncthreads();
        if (t == 0) carry += tmp[1023];
        __syncthreads();
    }
    if (t == 0) rowStart[n] = carry;
}

// ---------- 5. CSR build: scatter src ids by dst ----------
__global__ void scatter_kernel(const int* __restrict__ src, const int* __restrict__ dst,
                               const int* __restrict__ rowStart, int* __restrict__ cursor,
                               int* __restrict__ srcSorted) {
    int e = blockIdx.x * 256 + threadIdx.x;
    if (e < NEDGE) {
        int d = dst[e];
        int pos = rowStart[d] + atomicAdd(cursor + d, 1);
        srcSorted[pos] = src[e];
    }
}

// ---------- 6. fused per-destination attention: softmax + aggregate + GELU ----------
// One 64-lane wave per dst node. Lane l holds dims {2l, 2l+1}. Head h = lanes [16h,16h+16).
__global__ __launch_bounds__(256) void fused_attn(const int* __restrict__ rowStart,
                                                  const int* __restrict__ srcSorted,
                                                  const float* __restrict__ qkvD,  // dst (q at +0)
                                                  const float* __restrict__ qkvS,  // src (k at +128, v at +256)
                                                  float* __restrict__ out, int Ndst) {
    int node = (blockIdx.x * 256 + threadIdx.x) >> 6;
    int lane = threadIdx.x & 63;
    if (node >= Ndst) return;
    float2 q = *(const float2*)(qkvD + (size_t)node * 384 + 2 * lane);
    int beg = rowStart[node], end = rowStart[node + 1];
    float m = -INFINITY, s = 0.f, ax = 0.f, ay = 0.f;
    for (int i = beg; i < end; ++i) {
        int sid = srcSorted[i];
        const float* bp = qkvS + (size_t)sid * 384;
        float2 k2 = *(const float2*)(bp + 128 + 2 * lane);
        float2 v2 = *(const float2*)(bp + 256 + 2 * lane);
        float part = q.x * k2.x + q.y * k2.y;
        part += __shfl_xor(part, 1);
        part += __shfl_xor(part, 2);
        part += __shfl_xor(part, 4);
        part += __shfl_xor(part, 8);          // alpha for this head, uniform in 16-lane group
        float mn = fmaxf(m, part);
        float sc = expf(m - mn);              // first iter: exp(-inf)=0
        float a = expf(part - mn);
        s = s * sc + a;
        ax = ax * sc + a * v2.x;
        ay = ay * sc + a * v2.y;
        m = mn;
    }
    float den = s + 1e-16f;
    float2 r = make_float2(gelu_exact(ax / den), gelu_exact(ay / den));
    *(float2*)(out + (size_t)node * 128 + 2 * lane) = r;
}

// ---------- 7. column sum over genes ----------
__global__ __launch_bounds__(128) void colsum(const float* __restrict__ X, int N,
                                              float* __restrict__ out) {
    int c = threadIdx.x;   // 128
    float s = 0.f;
    for (int r = blockIdx.x; r < N; r += gridDim.x) s += X[(size_t)r * 128 + c];
    atomicAdd(out + c, s);
}

// ---------- 8. predictor MLP ----------
__global__ __launch_bounds__(128) void predictor(const float* __restrict__ Xd,
                                                 const float* __restrict__ gsum,
                                                 const int* __restrict__ didx,
                                                 const float* __restrict__ pW1,
                                                 const float* __restrict__ pb1,
                                                 const float* __restrict__ pW2,
                                                 const float* __restrict__ pb2,
                                                 float* __restrict__ out) {
    __shared__ float comb[256];
    __shared__ float red[128];
    int b = blockIdx.x, t = threadIdx.x;
    int dn = didx[b];
    comb[t]       = Xd[(size_t)dn * 128 + t];
    comb[128 + t] = gsum[t] * (1.f / 40000.f);
    __syncthreads();
    float acc = pb1[t];
    for (int i = 0; i < 256; i++) acc += comb[i] * pW1[i * 128 + t];
    acc = fmaxf(acc, 0.f);
    red[t] = acc * pW2[t];
    __syncthreads();
    for (int sft = 64; sft > 0; sft >>= 1) {
        if (t < sft) red[t] += red[t + sft];
        __syncthreads();
    }
    if (t == 0) out[b] = red[0] + pb2[0];
}

// ---------- launch ----------
extern "C" void kernel_launch(void* const* d_in, const int* in_sizes, int n_in,
                              void* d_out, int out_size, void* d_ws, size_t ws_size,
                              hipStream_t stream) {
    const float* x_drug = (const float*)d_in[0];
    const float* x_gene = (const float*)d_in[1];
    const float* kW = (const float*)d_in[2];
    const float* kb = (const float*)d_in[3];
    const float* qW = (const float*)d_in[4];
    const float* qb = (const float*)d_in[5];
    const float* vW = (const float*)d_in[6];
    const float* vb = (const float*)d_in[7];
    const float* aW = (const float*)d_in[8];
    const float* ab = (const float*)d_in[9];
    const float* skip = (const float*)d_in[10];
    const float* a_rel = (const float*)d_in[11];
    const float* m_rel = (const float*)d_in[12];
    const float* p_rel = (const float*)d_in[13];
    const float* pW1 = (const float*)d_in[14];
    const float* pb1 = (const float*)d_in[15];
    const float* pW2 = (const float*)d_in[16];
    const float* pb2 = (const float*)d_in[17];
    const int* e_dg_s = (const int*)d_in[18];
    const int* e_dg_d = (const int*)d_in[19];
    const int* e_gd_s = (const int*)d_in[20];
    const int* e_gd_d = (const int*)d_in[21];
    const int* drug_idx = (const int*)d_in[22];

    float* ws = (float*)d_ws;
    // workspace layout (float section)
    float* BF    = ws;                                  // 196608
    float* BB    = BF + 196608;                         // 3072
    float* QKVD  = BB + 3072;                           // 20000*384
    float* QKVG  = QKVD + (size_t)N_DRUG * 384;         // 40000*384
    float* XD0   = QKVG + (size_t)N_GENE * 384;
    float* XD1   = XD0 + (size_t)N_DRUG * 128;
    float* XG0   = XD1 + (size_t)N_DRUG * 128;
    float* XG1   = XG0 + (size_t)N_GENE * 128;
    float* NUMG  = XG1 + (size_t)N_GENE * 128;          // 40000*128
    float* NUMD  = NUMG + (size_t)N_GENE * 128;         // 20000*128
    float* GSUM  = NUMD + (size_t)N_DRUG * 128;         // 128
    // int section (CSR)
    int* rowG  = (int*)(GSUM + 128);                    // 40001
    int* rowD  = rowG + 40001;                          // 20001
    int* cntG  = rowD + 20001;                          // 40000 (also cursor)
    int* cntD  = cntG + 40000;                          // 20000 (also cursor)
    int* srcG  = cntD + 20000;                          // 800000: dg edges sorted by gene dst
    int* srcD  = srcG + NEDGE;                          // 800000: gd edges sorted by drug dst

    fuse_weights<<<768, 256, 0, stream>>>(kW, kb, qW, qb, vW, vb, a_rel, m_rel, p_rel, BF, BB);

    // ---- build CSR by destination (layer-invariant) ----
    const int gridE = (NEDGE + 255) / 256;
    hipMemsetAsync(cntG, 0, 40000 * sizeof(int), stream);
    hipMemsetAsync(cntD, 0, 20000 * sizeof(int), stream);
    hist_kernel<<<gridE, 256, 0, stream>>>(e_dg_d, cntG);
    hist_kernel<<<gridE, 256, 0, stream>>>(e_gd_d, cntD);
    exscan<<<1, 1024, 0, stream>>>(cntG, N_GENE, rowG);
    exscan<<<1, 1024, 0, stream>>>(cntD, N_DRUG, rowD);
    hipMemsetAsync(cntG, 0, 40000 * sizeof(int), stream);
    hipMemsetAsync(cntD, 0, 20000 * sizeof(int), stream);
    scatter_kernel<<<gridE, 256, 0, stream>>>(e_dg_s, e_dg_d, rowG, cntG, srcG);
    scatter_kernel<<<gridE, 256, 0, stream>>>(e_gd_s, e_gd_d, rowD, cntD, srcD);

    const float* xd_cur = x_drug;
    const float* xg_cur = x_gene;
    float* xd_bufs[2] = {XD0, XD1};
    float* xg_bufs[2] = {XG0, XG1};

    const int gridD = (N_DRUG + 63) / 64;   // 313
    const int gridG = (N_GENE + 63) / 64;   // 625

    for (int l = 0; l < 2; ++l) {
        const float* BFd = BF + (size_t)(l * 2 + 0) * 49152;
        const float* BFg = BF + (size_t)(l * 2 + 1) * 49152;
        const float* BBd = BB + (size_t)(l * 2 + 0) * 384;
        const float* BBg = BB + (size_t)(l * 2 + 1) * 384;

        gemm128<<<dim3(6, gridD), 256, 0, stream>>>(xd_cur, N_DRUG, BFd, 384, BBd, QKVD, 384, 0, nullptr, nullptr);
        gemm128<<<dim3(6, gridG), 256, 0, stream>>>(xg_cur, N_GENE, BFg, 384, BBg, QKVG, 384, 0, nullptr, nullptr);

        // edge type 0: drug -> gene  (dst genes): q from QKVG, k/v from QKVD
        fused_attn<<<(N_GENE + 3) / 4, 256, 0, stream>>>(rowG, srcG, QKVG, QKVD, NUMG, N_GENE);
        // edge type 1: gene -> drug  (dst drugs): q from QKVD, k/v from QKVG
        fused_attn<<<(N_DRUG + 3) / 4, 256, 0, stream>>>(rowD, srcD, QKVD, QKVG, NUMD, N_DRUG);

        float* xd_next = xd_bufs[l];
        float* xg_next = xg_bufs[l];
        gemm128<<<dim3(2, gridD), 256, 0, stream>>>(NUMD, N_DRUG, aW + (size_t)(l * 2 + 0) * 16384, 128,
                                                    ab + (size_t)(l * 2 + 0) * 128, xd_next, 128,
                                                    1, skip + (l * 2 + 0), xd_cur);
        gemm128<<<dim3(2, gridG), 256, 0, stream>>>(NUMG, N_GENE, aW + (size_t)(l * 2 + 1) * 16384, 128,
                                                    ab + (size_t)(l * 2 + 1) * 128, xg_next, 128,
                                                    1, skip + (l * 2 + 1), xg_cur);
        xd_cur = xd_next;
        xg_cur = xg_next;
    }

    hipMemsetAsync(GSUM, 0, 128 * sizeof(float), stream);
    colsum<<<256, 128, 0, stream>>>(xg_cur, N_GENE, GSUM);
    predictor<<<NBATCH, 128, 0, stream>>>(xd_cur, GSUM, drug_idx, pW1, pb1, pW2, pb2, (float*)d_out);
}